// Round 10
// baseline (413.667 us; speedup 1.0000x reference)
//
#include <hip/hip_runtime.h>
#include <hip/hip_bf16.h>
#include <stdint.h>

#define NODES 32768
#define DIM 256
#define ROWS17 17
#define LOG2E 1.4426950408889634f

typedef __attribute__((ext_vector_type(8))) short s16x8;
typedef __attribute__((ext_vector_type(8))) unsigned short u16x8;
typedef __attribute__((ext_vector_type(4))) float f32x4;

__device__ __forceinline__ unsigned short f2bf(float f) {
  union { __hip_bfloat16 h; unsigned short u; } c;
  c.h = __float2bfloat16(f);
  return c.u;
}
__device__ __forceinline__ unsigned int f2bf2(float a, float b) {
  union { __hip_bfloat162 h; unsigned int u; } c;
  c.h = __float22bfloat162_rn(make_float2(a, b));
  return c.u;
}
__device__ __forceinline__ float bf2f(unsigned short h) {
  return __uint_as_float(((unsigned int)h) << 16);
}
__device__ __forceinline__ float fsig(float x) {
  return __builtin_amdgcn_rcpf(1.0f + __builtin_amdgcn_exp2f(-LOG2E * x));
}
__device__ __forceinline__ float ftanh(float x) {
  float e = __builtin_amdgcn_exp2f(x * (2.0f * LOG2E));
  return __builtin_fmaf(-2.0f, __builtin_amdgcn_rcpf(1.0f + e), 1.0f);
}

// Wave-tile GEMM: M=64 (LDS bf16, XOR-swizzled 512B rows), N=32 (wave's column
// slice of BMAT), K=256. 8 waves cover N=256. acc[4][2] = 32 AGPRs.
// BIAS[nt] splatted into the accumulator init. NO setprio (R6: -100us).
#define GEMM64B(BMAT, ACC, BIAS)                                               \
  do {                                                                         \
    const s16x8* bp =                                                          \
        (const s16x8*)((BMAT) + ((wv * 32 + l15) * 256 + l4 * 8));             \
    _Pragma("unroll") for (int mt = 0; mt < 4; ++mt)                           \
        _Pragma("unroll") for (int nt = 0; nt < 2; ++nt)                       \
            ACC[mt][nt] = (f32x4)(BIAS[nt]);                                   \
    _Pragma("unroll") for (int ks = 0; ks < 8; ++ks) {                         \
      s16x8 afr[4];                                                            \
      s16x8 bfr[2];                                                            \
      int ab = (l15 * 512 + l4 * 16 + ks * 64) ^ ((l15 & 7) << 4);             \
      _Pragma("unroll") for (int mt = 0; mt < 4; ++mt)                         \
          afr[mt] = *(const s16x8*)(xab + (ab + mt * 8192));                   \
      _Pragma("unroll") for (int nt = 0; nt < 2; ++nt)                         \
          bfr[nt] = bp[nt * 512 + ks * 4];                                     \
      _Pragma("unroll") for (int mt = 0; mt < 4; ++mt)                         \
          _Pragma("unroll") for (int nt = 0; nt < 2; ++nt)                     \
              ACC[mt][nt] = __builtin_amdgcn_mfma_f32_16x16x32_bf16(           \
                  afr[mt], bfr[nt], ACC[mt][nt], 0, 0, 0);                     \
    }                                                                          \
  } while (0)

// Dual-B variant: two GEMMs sharing the A-fragment ds_reads (k_center hc+gc).
#define GEMM64D(BM1, BM2, ACC1, ACC2, BI1, BI2)                                \
  do {                                                                         \
    const s16x8* bp1 =                                                         \
        (const s16x8*)((BM1) + ((wv * 32 + l15) * 256 + l4 * 8));              \
    const s16x8* bp2 =                                                         \
        (const s16x8*)((BM2) + ((wv * 32 + l15) * 256 + l4 * 8));              \
    _Pragma("unroll") for (int mt = 0; mt < 4; ++mt)                           \
        _Pragma("unroll") for (int nt = 0; nt < 2; ++nt) {                     \
      ACC1[mt][nt] = (f32x4)(BI1[nt]);                                         \
      ACC2[mt][nt] = (f32x4)(BI2[nt]);                                         \
    }                                                                          \
    _Pragma("unroll") for (int ks = 0; ks < 8; ++ks) {                         \
      s16x8 afr[4];                                                            \
      s16x8 bfr1[2];                                                           \
      s16x8 bfr2[2];                                                           \
      int ab = (l15 * 512 + l4 * 16 + ks * 64) ^ ((l15 & 7) << 4);             \
      _Pragma("unroll") for (int mt = 0; mt < 4; ++mt)                         \
          afr[mt] = *(const s16x8*)(xab + (ab + mt * 8192));                   \
      _Pragma("unroll") for (int nt = 0; nt < 2; ++nt) {                       \
        bfr1[nt] = bp1[nt * 512 + ks * 4];                                     \
        bfr2[nt] = bp2[nt * 512 + ks * 4];                                     \
      }                                                                        \
      _Pragma("unroll") for (int mt = 0; mt < 4; ++mt)                         \
          _Pragma("unroll") for (int nt = 0; nt < 2; ++nt) {                   \
        ACC1[mt][nt] = __builtin_amdgcn_mfma_f32_16x16x32_bf16(                \
            afr[mt], bfr1[nt], ACC1[mt][nt], 0, 0, 0);                         \
        ACC2[mt][nt] = __builtin_amdgcn_mfma_f32_16x16x32_bf16(                \
            afr[mt], bfr2[nt], ACC2[mt][nt], 0, 0, 0);                         \
      }                                                                        \
    }                                                                          \
  } while (0)

// ---------------- K0: convert 5 weight matrices f32 -> bf16 ----------------
// Also zeroes the 3 global bucket counters (stream-serial before k_sort).
__global__ __launch_bounds__(256) void k_cvtw(const float* __restrict__ w0,
                                              const float* __restrict__ w1,
                                              const float* __restrict__ w2,
                                              const float* __restrict__ w3,
                                              const float* __restrict__ w4,
                                              unsigned short* __restrict__ dst,
                                              int* __restrict__ gcnt) {
  if (blockIdx.x == 0 && threadIdx.x < 3) gcnt[threadIdx.x] = 0;
  int idx = (blockIdx.x * 256 + threadIdx.x) * 8;  // 160 blocks -> 327680 els
  int which = idx >> 16;
  int off = idx & 65535;
  const float* src = which == 0 ? w0 : which == 1 ? w1 : which == 2 ? w2
                   : which == 3 ? w3 : w4;
  const f32x4* s4 = (const f32x4*)(src + off);
  f32x4 a = s4[0], b = s4[1];
  u16x8 v;
  unsigned int* vp = (unsigned int*)&v;
  vp[0] = f2bf2(a[0], a[1]);
  vp[1] = f2bf2(a[2], a[3]);
  vp[2] = f2bf2(b[0], b[1]);
  vp[3] = f2bf2(b[2], b[3]);
  *(u16x8*)(dst + idx) = v;
}

// ---------------- K-sort: bucket nodes by nv into fixed regions ------------
__global__ __launch_bounds__(512) void k_sort(const int* __restrict__ counts,
                                              int* __restrict__ perm,
                                              int* __restrict__ gcnt) {
  __shared__ int h[3];
  __shared__ int base[3];
  const int tid = threadIdx.x;
  if (tid < 3) h[tid] = 0;
  __syncthreads();
  int node = blockIdx.x * 512 + tid;
  int nv = counts[node] + 1;
  int b = nv <= 4 ? 0 : nv <= 8 ? 1 : 2;
  int slot = atomicAdd(&h[b], 1);
  __syncthreads();
  if (tid < 3) base[tid] = atomicAdd(&gcnt[tid], h[tid]);
  __syncthreads();
  perm[b * NODES + base[b] + slot] = node;
}

// ---------------- K1: centers -> cp (tanh), hc, gc ----------------
__global__ __launch_bounds__(512) void k_center(
    const float* __restrict__ x, const unsigned short* __restrict__ wxb,
    const unsigned short* __restrict__ whb, const unsigned short* __restrict__ wgb,
    const float* __restrict__ wx_bias, const float* __restrict__ wh_bias,
    const float* __restrict__ wg_bias, unsigned short* __restrict__ cpw,
    unsigned short* __restrict__ hcw, unsigned short* __restrict__ gcw) {
  __shared__ unsigned short XA[64 * 256];
  char* xab = (char*)XA;
  const int tid = threadIdx.x;
  const int lane = tid & 63;
  const int wv = tid >> 6;
  const int l15 = lane & 15;
  const int l4 = lane >> 4;
  const int n0 = blockIdx.x * 64;

#pragma unroll
  for (int i = 0; i < 4; ++i) {
    int chunk = i * 512 + tid;
    int row = chunk >> 5;
    int e0 = (chunk & 31) * 8;
    int node = n0 + row;
    const f32x4* s4 = (const f32x4*)(x + (node * (ROWS17 * DIM) + e0));
    f32x4 f0 = s4[0], f1 = s4[1];
    u16x8 v;
    unsigned int* vp = (unsigned int*)&v;
    vp[0] = f2bf2(f0[0], f0[1]);
    vp[1] = f2bf2(f0[2], f0[3]);
    vp[2] = f2bf2(f1[0], f1[1]);
    vp[3] = f2bf2(f1[2], f1[3]);
    *(u16x8*)(xab + ((row * 512 + e0 * 2) ^ ((row & 7) << 4))) = v;
  }
  __syncthreads();

  float b1[2];
#pragma unroll
  for (int nt = 0; nt < 2; ++nt) b1[nt] = wx_bias[wv * 32 + nt * 16 + l15];
  f32x4 acc[4][2];
  GEMM64B(wxb, acc, b1);
  __syncthreads();

  // cp = tanh(acc) -> back into XA (swizzled); bias already in acc
#pragma unroll
  for (int mt = 0; mt < 4; ++mt) {
#pragma unroll
    for (int nt = 0; nt < 2; ++nt) {
      int h = wv * 32 + nt * 16 + l15;
#pragma unroll
      for (int r = 0; r < 4; ++r) {
        int rl = mt * 16 + 4 * l4 + r;
        unsigned short o = f2bf(ftanh(acc[mt][nt][r]));
        *(unsigned short*)(xab + ((rl * 512 + h * 2) ^ ((rl & 7) << 4))) = o;
      }
    }
  }
  __syncthreads();

#pragma unroll
  for (int i = 0; i < 4; ++i) {
    int chunk = i * 512 + tid;
    int row = chunk >> 5;
    int e0 = (chunk & 31) * 8;
    u16x8 v = *(const u16x8*)(xab + ((row * 512 + e0 * 2) ^ ((row & 7) << 4)));
    *(u16x8*)(cpw + ((n0 + row) * 256 + e0)) = v;
  }

  // hc and gc in one dual pass (shared A-fragment reads)
  float b2[2], b3[2];
#pragma unroll
  for (int nt = 0; nt < 2; ++nt) {
    b2[nt] = wh_bias[wv * 32 + nt * 16 + l15];
    b3[nt] = wg_bias[wv * 32 + nt * 16 + l15];
  }
  f32x4 acc2[4][2];
  GEMM64D(whb, wgb, acc, acc2, b2, b3);
#pragma unroll
  for (int mt = 0; mt < 4; ++mt)
#pragma unroll
    for (int nt = 0; nt < 2; ++nt) {
      int h = wv * 32 + nt * 16 + l15;
#pragma unroll
      for (int r = 0; r < 4; ++r) {
        int rl = mt * 16 + 4 * l4 + r;
        hcw[(n0 + rl) * 256 + h] = f2bf(acc[mt][nt][r]);
        gcw[(n0 + rl) * 256 + h] = f2bf(acc2[mt][nt][r]);
      }
    }
}

// ---------------- K2: neighbors -> proj -> temp -> softmax -> con -> out ---
// Bucketed: block covers 64 rows = npb nodes x Mn rows, Mn=1<<s in {4,8,16}.
// R10: k_final fused in -- con goes to CN (LDS), mini-GEMM M=16 vs Ug, gate
// and out written directly. No conw global round-trip, no k_final dispatch.
__global__ __launch_bounds__(512, 4) void k_neigh(
    const float* __restrict__ x, const int* __restrict__ counts,
    const unsigned short* __restrict__ wxb, const unsigned short* __restrict__ uhb,
    const unsigned short* __restrict__ ugb, const float* __restrict__ wx_bias,
    const float* __restrict__ uh_bias, const float* __restrict__ ug_bias,
    const unsigned short* __restrict__ hcw, const unsigned short* __restrict__ cpw,
    const unsigned short* __restrict__ gcw, float* __restrict__ out,
    const int* __restrict__ perm, const int* __restrict__ bcnt) {
  __shared__ unsigned short XA[64 * 256];
  __shared__ unsigned short HC[16 * 256];
  __shared__ unsigned short CN[16 * 256];
  __shared__ int ndl[16];
  __shared__ int nvs[16];
  char* xab = (char*)XA;
  char* cnb = (char*)CN;
  const int tid = threadIdx.x;
  const int lane = tid & 63;
  const int wv = tid >> 6;
  const int l15 = lane & 15;
  const int l4 = lane >> 4;

  // --- bucket geometry (block-uniform); perm regions at b*NODES ---
  int c0 = bcnt[0], c1 = bcnt[1], c2 = bcnt[2];
  int nb0 = (c0 + 15) >> 4, nb1 = (c1 + 7) >> 3, nb2 = (c2 + 3) >> 2;
  int b = blockIdx.x;
  int s, npb, pbase, valid;
  if (b < nb0) {
    s = 2; npb = 16; pbase = b * 16;
    valid = c0 - b * 16; valid = valid > 16 ? 16 : valid;
  } else if (b < nb0 + nb1) {
    s = 3; npb = 8; int bb = b - nb0; pbase = NODES + bb * 8;
    valid = c1 - bb * 8; valid = valid > 8 ? 8 : valid;
  } else if (b < nb0 + nb1 + nb2) {
    s = 4; npb = 4; int bb = b - nb0 - nb1; pbase = 2 * NODES + bb * 4;
    valid = c2 - bb * 4; valid = valid > 4 ? 4 : valid;
  } else {
    return;
  }
  const int mn1 = (1 << s) - 1;

  if (tid < npb) {
    int nd = (tid < valid) ? perm[pbase + tid] : 0;
    ndl[tid] = nd;
    nvs[tid] = (tid < valid) ? counts[nd] + 1 : 0;
  }
  __syncthreads();

  // stage hc for the block's nodes
  if (tid < npb * 32) {
    int j = tid >> 5;
    int e0 = (tid & 31) * 8;
    if (j < valid)
      *(u16x8*)(HC + j * 256 + e0) = *(const u16x8*)(hcw + (ndl[j] * 256 + e0));
  }

  // stage neighbor rows; rows with nrow >= nv stored as 0
#pragma unroll
  for (int i = 0; i < 4; ++i) {
    int chunk = i * 512 + tid;
    int row = chunk >> 5;
    int e0 = (chunk & 31) * 8;
    int j = row >> s;
    int nrow = row & mn1;
    u16x8 v;
    if (nrow < nvs[j]) {
      const f32x4* s4 =
          (const f32x4*)(x + ((ndl[j] * ROWS17 + 1 + nrow) * DIM + e0));
      f32x4 f0 = s4[0], f1 = s4[1];
      unsigned int* vp = (unsigned int*)&v;
      vp[0] = f2bf2(f0[0], f0[1]);
      vp[1] = f2bf2(f0[2], f0[3]);
      vp[2] = f2bf2(f1[0], f1[1]);
      vp[3] = f2bf2(f1[2], f1[3]);
    } else {
#pragma unroll
      for (int jj = 0; jj < 8; ++jj) v[jj] = 0;
    }
    *(u16x8*)(xab + ((row * 512 + e0 * 2) ^ ((row & 7) << 4))) = v;
  }
  __syncthreads();

  float b1[2];
#pragma unroll
  for (int nt = 0; nt < 2; ++nt) b1[nt] = wx_bias[wv * 32 + nt * 16 + l15];
  f32x4 acc[4][2];
  GEMM64B(wxb, acc, b1);  // proj pre-act (bias in acc)
  __syncthreads();

  // proj = tanh(acc): bf16 -> XA (for GEMM2), f32 -> regs (for softmax).
  float preg[4][2][4];
#pragma unroll
  for (int mt = 0; mt < 4; ++mt) {
#pragma unroll
    for (int nt = 0; nt < 2; ++nt) {
      int h = wv * 32 + nt * 16 + l15;
#pragma unroll
      for (int r = 0; r < 4; ++r) {
        int row = mt * 16 + 4 * l4 + r;
        float t = ftanh(acc[mt][nt][r]);
        preg[mt][nt][r] = t;
        *(unsigned short*)(xab + ((row * 512 + h * 2) ^ ((row & 7) << 4))) =
            f2bf(t);
      }
    }
  }
  __syncthreads();

  float b2[2];
#pragma unroll
  for (int nt = 0; nt < 2; ++nt) b2[nt] = uh_bias[wv * 32 + nt * 16 + l15];
  GEMM64B(uhb, acc, b2);  // temp pre-act (Uh_b in acc; still need +hc)

  const int wmask = (1 << (s - 2)) - 1;  // writer: (l4 & wmask)==0
#pragma unroll
  for (int mt = 0; mt < 4; ++mt) {
    int j = (mt * 16 + 4 * l4) >> s;  // r never crosses a node boundary
    int nv = nvs[j];
#pragma unroll
    for (int nt = 0; nt < 2; ++nt) {
      int g = wv * 32 + nt * 16 + l15;
      float base = bf2f(HC[j * 256 + g]);
      float e[4];
#pragma unroll
      for (int r = 0; r < 4; ++r) {
        int k = (4 * l4 + r) & mn1;
        float sg = fsig(acc[mt][nt][r] + base);
        e[r] = (k < nv) ? __builtin_amdgcn_exp2f(LOG2E * sg) : 0.0f;
      }
      float Z = (e[0] + e[1]) + (e[2] + e[3]);
      float num = e[0] * preg[mt][nt][0] + e[1] * preg[mt][nt][1] +
                  e[2] * preg[mt][nt][2] + e[3] * preg[mt][nt][3];
      if (s >= 3) {
        Z += __shfl_xor(Z, 16);
        num += __shfl_xor(num, 16);
      }
      if (s == 4) {
        Z += __shfl_xor(Z, 32);
        num += __shfl_xor(num, 32);
      }
      // con -> CN row j (bf16, swizzled). CN unread until next barrier.
      if ((l4 & wmask) == 0 && j < valid)
        *(unsigned short*)(cnb + ((j * 512 + g * 2) ^ ((j & 7) << 4))) =
            f2bf(num * __builtin_amdgcn_rcpf(Z));
    }
  }
  __syncthreads();

  // mini-GEMM M=16: cg = con @ Ug^T + Ug_b for this block's nodes.
  // CN rows >= valid are garbage (masked at the out-write).
  float bg[2];
#pragma unroll
  for (int nt = 0; nt < 2; ++nt) bg[nt] = ug_bias[wv * 32 + nt * 16 + l15];
  f32x4 acc3[2];
  {
    const s16x8* bp =
        (const s16x8*)(ugb + ((wv * 32 + l15) * 256 + l4 * 8));
#pragma unroll
    for (int nt = 0; nt < 2; ++nt) acc3[nt] = (f32x4)(bg[nt]);
#pragma unroll
    for (int ks = 0; ks < 8; ++ks) {
      s16x8 afr = *(const s16x8*)(
          cnb + ((l15 * 512 + l4 * 16 + ks * 64) ^ ((l15 & 7) << 4)));
#pragma unroll
      for (int nt = 0; nt < 2; ++nt)
        acc3[nt] = __builtin_amdgcn_mfma_f32_16x16x32_bf16(
            afr, bp[nt * 512 + ks * 4], acc3[nt], 0, 0, 0);
    }
  }
#pragma unroll
  for (int nt = 0; nt < 2; ++nt) {
    int g = wv * 32 + nt * 16 + l15;
#pragma unroll
    for (int r = 0; r < 4; ++r) {
      int nr = 4 * l4 + r;
      if (nr < valid) {
        int nd = ndl[nr];
        float gate = fsig(bf2f(gcw[nd * 256 + g]) + acc3[nt][r]);
        float cpv = bf2f(cpw[nd * 256 + g]);
        float cnv = bf2f(*(const unsigned short*)(
            cnb + ((nr * 512 + g * 2) ^ ((nr & 7) << 4))));
        out[nd * 256 + g] = gate * cpv + (1.0f - gate) * cnv;
      }
    }
  }
}

extern "C" void kernel_launch(void* const* d_in, const int* in_sizes, int n_in,
                              void* d_out, int out_size, void* d_ws, size_t ws_size,
                              hipStream_t stream) {
  (void)in_sizes; (void)n_in; (void)out_size; (void)ws_size;
  const float* x = (const float*)d_in[0];
  const int* counts = (const int*)d_in[1];
  const float* Wx_w = (const float*)d_in[2];
  const float* Wx_b = (const float*)d_in[3];
  const float* Wh_w = (const float*)d_in[4];
  const float* Wh_b = (const float*)d_in[5];
  const float* Uh_w = (const float*)d_in[6];
  const float* Uh_b = (const float*)d_in[7];
  const float* Wg_w = (const float*)d_in[8];
  const float* Wg_b = (const float*)d_in[9];
  const float* Ug_w = (const float*)d_in[10];
  const float* Ug_b = (const float*)d_in[11];

  unsigned short* ws = (unsigned short*)d_ws;
  unsigned short* wxb = ws;                    // 65536 els each
  unsigned short* whb = ws + 65536;
  unsigned short* uhb = ws + 131072;
  unsigned short* wgb = ws + 196608;
  unsigned short* ugb = ws + 262144;
  unsigned short* cpw = ws + 327680;           // 32768*256 els each
  unsigned short* hcw = cpw + NODES * 256;
  unsigned short* gcw = hcw + NODES * 256;
  unsigned short* conw = gcw + NODES * 256;    // unused (kept for layout)
  int* perm = (int*)(conw + NODES * 256);      // 3*NODES ints (fixed regions)
  int* gcnt = perm + 3 * NODES;                // 3 ints
  float* out = (float*)d_out;

  hipLaunchKernelGGL(k_cvtw, dim3(160), dim3(256), 0, stream,
                     Wx_w, Wh_w, Uh_w, Wg_w, Ug_w, ws, gcnt);
  hipLaunchKernelGGL(k_sort, dim3(NODES / 512), dim3(512), 0, stream,
                     counts, perm, gcnt);
  hipLaunchKernelGGL(k_center, dim3(NODES / 64), dim3(512), 0, stream,
                     x, wxb, whb, wgb, Wx_b, Wh_b, Wg_b, cpw, hcw, gcw);
  hipLaunchKernelGGL(k_neigh, dim3(NODES / 4 + 3), dim3(512), 0, stream,
                     x, counts, wxb, uhb, ugb, Wx_b, Uh_b, Ug_b,
                     hcw, cpw, gcw, out, perm, gcnt);
}

// Round 11
// 305.216 us; speedup vs baseline: 1.3553x; 1.3553x over previous
//
#include <hip/hip_runtime.h>
#include <hip/hip_bf16.h>
#include <stdint.h>

#define NODES 32768
#define DIM 256
#define ROWS17 17
#define LOG2E 1.4426950408889634f

typedef __attribute__((ext_vector_type(8))) short s16x8;
typedef __attribute__((ext_vector_type(8))) unsigned short u16x8;
typedef __attribute__((ext_vector_type(4))) float f32x4;

__device__ __forceinline__ unsigned short f2bf(float f) {
  union { __hip_bfloat16 h; unsigned short u; } c;
  c.h = __float2bfloat16(f);
  return c.u;
}
__device__ __forceinline__ unsigned int f2bf2(float a, float b) {
  union { __hip_bfloat162 h; unsigned int u; } c;
  c.h = __float22bfloat162_rn(make_float2(a, b));
  return c.u;
}
__device__ __forceinline__ float bf2f(unsigned short h) {
  return __uint_as_float(((unsigned int)h) << 16);
}
__device__ __forceinline__ float fsig(float x) {
  return __builtin_amdgcn_rcpf(1.0f + __builtin_amdgcn_exp2f(-LOG2E * x));
}
__device__ __forceinline__ float ftanh(float x) {
  float e = __builtin_amdgcn_exp2f(x * (2.0f * LOG2E));
  return __builtin_fmaf(-2.0f, __builtin_amdgcn_rcpf(1.0f + e), 1.0f);
}

// Wave-tile GEMM: M=64 (LDS bf16, XOR-swizzled 512B rows), N=32 (wave's column
// slice of BMAT), K=256. 8 waves cover N=256. acc[4][2] = 32 AGPRs.
// BIAS[nt] splatted into the accumulator init. NO setprio (R6: -100us).
#define GEMM64B(BMAT, ACC, BIAS)                                               \
  do {                                                                         \
    const s16x8* bp =                                                          \
        (const s16x8*)((BMAT) + ((wv * 32 + l15) * 256 + l4 * 8));             \
    _Pragma("unroll") for (int mt = 0; mt < 4; ++mt)                           \
        _Pragma("unroll") for (int nt = 0; nt < 2; ++nt)                       \
            ACC[mt][nt] = (f32x4)(BIAS[nt]);                                   \
    _Pragma("unroll") for (int ks = 0; ks < 8; ++ks) {                         \
      s16x8 afr[4];                                                            \
      s16x8 bfr[2];                                                            \
      int ab = (l15 * 512 + l4 * 16 + ks * 64) ^ ((l15 & 7) << 4);             \
      _Pragma("unroll") for (int mt = 0; mt < 4; ++mt)                         \
          afr[mt] = *(const s16x8*)(xab + (ab + mt * 8192));                   \
      _Pragma("unroll") for (int nt = 0; nt < 2; ++nt)                         \
          bfr[nt] = bp[nt * 512 + ks * 4];                                     \
      _Pragma("unroll") for (int mt = 0; mt < 4; ++mt)                         \
          _Pragma("unroll") for (int nt = 0; nt < 2; ++nt)                     \
              ACC[mt][nt] = __builtin_amdgcn_mfma_f32_16x16x32_bf16(           \
                  afr[mt], bfr[nt], ACC[mt][nt], 0, 0, 0);                     \
    }                                                                          \
  } while (0)

// Dual-B variant: two GEMMs sharing the A-fragment ds_reads (k_center hc+gc).
#define GEMM64D(BM1, BM2, ACC1, ACC2, BI1, BI2)                                \
  do {                                                                         \
    const s16x8* bp1 =                                                         \
        (const s16x8*)((BM1) + ((wv * 32 + l15) * 256 + l4 * 8));              \
    const s16x8* bp2 =                                                         \
        (const s16x8*)((BM2) + ((wv * 32 + l15) * 256 + l4 * 8));              \
    _Pragma("unroll") for (int mt = 0; mt < 4; ++mt)                           \
        _Pragma("unroll") for (int nt = 0; nt < 2; ++nt) {                     \
      ACC1[mt][nt] = (f32x4)(BI1[nt]);                                         \
      ACC2[mt][nt] = (f32x4)(BI2[nt]);                                         \
    }                                                                          \
    _Pragma("unroll") for (int ks = 0; ks < 8; ++ks) {                         \
      s16x8 afr[4];                                                            \
      s16x8 bfr1[2];                                                           \
      s16x8 bfr2[2];                                                           \
      int ab = (l15 * 512 + l4 * 16 + ks * 64) ^ ((l15 & 7) << 4);             \
      _Pragma("unroll") for (int mt = 0; mt < 4; ++mt)                         \
          afr[mt] = *(const s16x8*)(xab + (ab + mt * 8192));                   \
      _Pragma("unroll") for (int nt = 0; nt < 2; ++nt) {                       \
        bfr1[nt] = bp1[nt * 512 + ks * 4];                                     \
        bfr2[nt] = bp2[nt * 512 + ks * 4];                                     \
      }                                                                        \
      _Pragma("unroll") for (int mt = 0; mt < 4; ++mt)                         \
          _Pragma("unroll") for (int nt = 0; nt < 2; ++nt) {                   \
        ACC1[mt][nt] = __builtin_amdgcn_mfma_f32_16x16x32_bf16(                \
            afr[mt], bfr1[nt], ACC1[mt][nt], 0, 0, 0);                         \
        ACC2[mt][nt] = __builtin_amdgcn_mfma_f32_16x16x32_bf16(                \
            afr[mt], bfr2[nt], ACC2[mt][nt], 0, 0, 0);                         \
      }                                                                        \
    }                                                                          \
  } while (0)

// ---------------- K0: convert 5 weight matrices f32 -> bf16 ----------------
// Also zeroes the 3 global bucket counters (stream-serial before k_sort).
__global__ __launch_bounds__(256) void k_cvtw(const float* __restrict__ w0,
                                              const float* __restrict__ w1,
                                              const float* __restrict__ w2,
                                              const float* __restrict__ w3,
                                              const float* __restrict__ w4,
                                              unsigned short* __restrict__ dst,
                                              int* __restrict__ gcnt) {
  if (blockIdx.x == 0 && threadIdx.x < 3) gcnt[threadIdx.x] = 0;
  int idx = (blockIdx.x * 256 + threadIdx.x) * 8;  // 160 blocks -> 327680 els
  int which = idx >> 16;
  int off = idx & 65535;
  const float* src = which == 0 ? w0 : which == 1 ? w1 : which == 2 ? w2
                   : which == 3 ? w3 : w4;
  const f32x4* s4 = (const f32x4*)(src + off);
  f32x4 a = s4[0], b = s4[1];
  u16x8 v;
  unsigned int* vp = (unsigned int*)&v;
  vp[0] = f2bf2(a[0], a[1]);
  vp[1] = f2bf2(a[2], a[3]);
  vp[2] = f2bf2(b[0], b[1]);
  vp[3] = f2bf2(b[2], b[3]);
  *(u16x8*)(dst + idx) = v;
}

// ---------------- K-sort: bucket nodes by nv into fixed regions ------------
__global__ __launch_bounds__(512) void k_sort(const int* __restrict__ counts,
                                              int* __restrict__ perm,
                                              int* __restrict__ gcnt) {
  __shared__ int h[3];
  __shared__ int base[3];
  const int tid = threadIdx.x;
  if (tid < 3) h[tid] = 0;
  __syncthreads();
  int node = blockIdx.x * 512 + tid;
  int nv = counts[node] + 1;
  int b = nv <= 4 ? 0 : nv <= 8 ? 1 : 2;
  int slot = atomicAdd(&h[b], 1);
  __syncthreads();
  if (tid < 3) base[tid] = atomicAdd(&gcnt[tid], h[tid]);
  __syncthreads();
  perm[b * NODES + base[b] + slot] = node;
}

// ---------------- K1: centers -> cp (tanh), hc, gc ----------------
__global__ __launch_bounds__(512) void k_center(
    const float* __restrict__ x, const unsigned short* __restrict__ wxb,
    const unsigned short* __restrict__ whb, const unsigned short* __restrict__ wgb,
    const float* __restrict__ wx_bias, const float* __restrict__ wh_bias,
    const float* __restrict__ wg_bias, unsigned short* __restrict__ cpw,
    unsigned short* __restrict__ hcw, unsigned short* __restrict__ gcw) {
  __shared__ unsigned short XA[64 * 256];
  char* xab = (char*)XA;
  const int tid = threadIdx.x;
  const int lane = tid & 63;
  const int wv = tid >> 6;
  const int l15 = lane & 15;
  const int l4 = lane >> 4;
  const int n0 = blockIdx.x * 64;

#pragma unroll
  for (int i = 0; i < 4; ++i) {
    int chunk = i * 512 + tid;
    int row = chunk >> 5;
    int e0 = (chunk & 31) * 8;
    int node = n0 + row;
    const f32x4* s4 = (const f32x4*)(x + (node * (ROWS17 * DIM) + e0));
    f32x4 f0 = s4[0], f1 = s4[1];
    u16x8 v;
    unsigned int* vp = (unsigned int*)&v;
    vp[0] = f2bf2(f0[0], f0[1]);
    vp[1] = f2bf2(f0[2], f0[3]);
    vp[2] = f2bf2(f1[0], f1[1]);
    vp[3] = f2bf2(f1[2], f1[3]);
    *(u16x8*)(xab + ((row * 512 + e0 * 2) ^ ((row & 7) << 4))) = v;
  }
  __syncthreads();

  float b1[2];
#pragma unroll
  for (int nt = 0; nt < 2; ++nt) b1[nt] = wx_bias[wv * 32 + nt * 16 + l15];
  f32x4 acc[4][2];
  GEMM64B(wxb, acc, b1);
  __syncthreads();

  // cp = tanh(acc) -> back into XA (swizzled); bias already in acc
#pragma unroll
  for (int mt = 0; mt < 4; ++mt) {
#pragma unroll
    for (int nt = 0; nt < 2; ++nt) {
      int h = wv * 32 + nt * 16 + l15;
#pragma unroll
      for (int r = 0; r < 4; ++r) {
        int rl = mt * 16 + 4 * l4 + r;
        unsigned short o = f2bf(ftanh(acc[mt][nt][r]));
        *(unsigned short*)(xab + ((rl * 512 + h * 2) ^ ((rl & 7) << 4))) = o;
      }
    }
  }
  __syncthreads();

#pragma unroll
  for (int i = 0; i < 4; ++i) {
    int chunk = i * 512 + tid;
    int row = chunk >> 5;
    int e0 = (chunk & 31) * 8;
    u16x8 v = *(const u16x8*)(xab + ((row * 512 + e0 * 2) ^ ((row & 7) << 4)));
    *(u16x8*)(cpw + ((n0 + row) * 256 + e0)) = v;
  }

  // hc and gc in one dual pass (shared A-fragment reads)
  float b2[2], b3[2];
#pragma unroll
  for (int nt = 0; nt < 2; ++nt) {
    b2[nt] = wh_bias[wv * 32 + nt * 16 + l15];
    b3[nt] = wg_bias[wv * 32 + nt * 16 + l15];
  }
  f32x4 acc2[4][2];
  GEMM64D(whb, wgb, acc, acc2, b2, b3);
#pragma unroll
  for (int mt = 0; mt < 4; ++mt)
#pragma unroll
    for (int nt = 0; nt < 2; ++nt) {
      int h = wv * 32 + nt * 16 + l15;
#pragma unroll
      for (int r = 0; r < 4; ++r) {
        int rl = mt * 16 + 4 * l4 + r;
        hcw[(n0 + rl) * 256 + h] = f2bf(acc[mt][nt][r]);
        gcw[(n0 + rl) * 256 + h] = f2bf(acc2[mt][nt][r]);
      }
    }
}

// ---------------- K2: neighbors -> proj -> temp -> softmax -> con ----------
// Bucketed: block covers 64 rows = npb nodes x Mn rows, Mn=1<<s in {4,8,16}.
__global__ __launch_bounds__(512, 4) void k_neigh(
    const float* __restrict__ x, const int* __restrict__ counts,
    const unsigned short* __restrict__ wxb, const unsigned short* __restrict__ uhb,
    const float* __restrict__ wx_bias, const float* __restrict__ uh_bias,
    const unsigned short* __restrict__ hcw, unsigned short* __restrict__ conw,
    const int* __restrict__ perm, const int* __restrict__ bcnt) {
  __shared__ unsigned short XA[64 * 256];
  __shared__ unsigned short HC[16 * 256];
  __shared__ int ndl[16];
  __shared__ int nvs[16];
  char* xab = (char*)XA;
  const int tid = threadIdx.x;
  const int lane = tid & 63;
  const int wv = tid >> 6;
  const int l15 = lane & 15;
  const int l4 = lane >> 4;

  // --- bucket geometry (block-uniform); perm regions at b*NODES ---
  int c0 = bcnt[0], c1 = bcnt[1], c2 = bcnt[2];
  int nb0 = (c0 + 15) >> 4, nb1 = (c1 + 7) >> 3, nb2 = (c2 + 3) >> 2;
  int b = blockIdx.x;
  int s, npb, pbase, valid;
  if (b < nb0) {
    s = 2; npb = 16; pbase = b * 16;
    valid = c0 - b * 16; valid = valid > 16 ? 16 : valid;
  } else if (b < nb0 + nb1) {
    s = 3; npb = 8; int bb = b - nb0; pbase = NODES + bb * 8;
    valid = c1 - bb * 8; valid = valid > 8 ? 8 : valid;
  } else if (b < nb0 + nb1 + nb2) {
    s = 4; npb = 4; int bb = b - nb0 - nb1; pbase = 2 * NODES + bb * 4;
    valid = c2 - bb * 4; valid = valid > 4 ? 4 : valid;
  } else {
    return;
  }
  const int mn1 = (1 << s) - 1;

  if (tid < npb) {
    int nd = (tid < valid) ? perm[pbase + tid] : 0;
    ndl[tid] = nd;
    nvs[tid] = (tid < valid) ? counts[nd] + 1 : 0;
  }
  __syncthreads();

  // stage hc for the block's nodes
  if (tid < npb * 32) {
    int j = tid >> 5;
    int e0 = (tid & 31) * 8;
    if (j < valid)
      *(u16x8*)(HC + j * 256 + e0) = *(const u16x8*)(hcw + (ndl[j] * 256 + e0));
  }

  // stage neighbor rows; rows with nrow >= nv stored as 0
#pragma unroll
  for (int i = 0; i < 4; ++i) {
    int chunk = i * 512 + tid;
    int row = chunk >> 5;
    int e0 = (chunk & 31) * 8;
    int j = row >> s;
    int nrow = row & mn1;
    u16x8 v;
    if (nrow < nvs[j]) {
      const f32x4* s4 =
          (const f32x4*)(x + ((ndl[j] * ROWS17 + 1 + nrow) * DIM + e0));
      f32x4 f0 = s4[0], f1 = s4[1];
      unsigned int* vp = (unsigned int*)&v;
      vp[0] = f2bf2(f0[0], f0[1]);
      vp[1] = f2bf2(f0[2], f0[3]);
      vp[2] = f2bf2(f1[0], f1[1]);
      vp[3] = f2bf2(f1[2], f1[3]);
    } else {
#pragma unroll
      for (int jj = 0; jj < 8; ++jj) v[jj] = 0;
    }
    *(u16x8*)(xab + ((row * 512 + e0 * 2) ^ ((row & 7) << 4))) = v;
  }
  __syncthreads();

  float b1[2];
#pragma unroll
  for (int nt = 0; nt < 2; ++nt) b1[nt] = wx_bias[wv * 32 + nt * 16 + l15];
  f32x4 acc[4][2];
  GEMM64B(wxb, acc, b1);  // proj pre-act (bias in acc)
  __syncthreads();

  // proj = tanh(acc): bf16 -> XA (for GEMM2), f32 -> regs (for softmax).
  float preg[4][2][4];
#pragma unroll
  for (int mt = 0; mt < 4; ++mt) {
#pragma unroll
    for (int nt = 0; nt < 2; ++nt) {
      int h = wv * 32 + nt * 16 + l15;
#pragma unroll
      for (int r = 0; r < 4; ++r) {
        int row = mt * 16 + 4 * l4 + r;
        float t = ftanh(acc[mt][nt][r]);
        preg[mt][nt][r] = t;
        *(unsigned short*)(xab + ((row * 512 + h * 2) ^ ((row & 7) << 4))) =
            f2bf(t);
      }
    }
  }
  __syncthreads();

  float b2[2];
#pragma unroll
  for (int nt = 0; nt < 2; ++nt) b2[nt] = uh_bias[wv * 32 + nt * 16 + l15];
  GEMM64B(uhb, acc, b2);  // temp pre-act (Uh_b in acc; still need +hc)

  const int wmask = (1 << (s - 2)) - 1;  // writer: (l4 & wmask)==0
#pragma unroll
  for (int mt = 0; mt < 4; ++mt) {
    int j = (mt * 16 + 4 * l4) >> s;  // r never crosses a node boundary
    int nv = nvs[j];
#pragma unroll
    for (int nt = 0; nt < 2; ++nt) {
      int g = wv * 32 + nt * 16 + l15;
      float base = bf2f(HC[j * 256 + g]);
      float e[4];
#pragma unroll
      for (int r = 0; r < 4; ++r) {
        int k = (4 * l4 + r) & mn1;
        float sg = fsig(acc[mt][nt][r] + base);
        e[r] = (k < nv) ? __builtin_amdgcn_exp2f(LOG2E * sg) : 0.0f;
      }
      float Z = (e[0] + e[1]) + (e[2] + e[3]);
      float num = e[0] * preg[mt][nt][0] + e[1] * preg[mt][nt][1] +
                  e[2] * preg[mt][nt][2] + e[3] * preg[mt][nt][3];
      if (s >= 3) {
        Z += __shfl_xor(Z, 16);
        num += __shfl_xor(num, 16);
      }
      if (s == 4) {
        Z += __shfl_xor(Z, 32);
        num += __shfl_xor(num, 32);
      }
      if ((l4 & wmask) == 0 && j < valid)
        conw[ndl[j] * 256 + g] = f2bf(num * __builtin_amdgcn_rcpf(Z));
    }
  }
}

// ---------------- K3: cg = con @ Ug^T, gate, out ----------------
__global__ __launch_bounds__(512, 4) void k_final(
    const unsigned short* __restrict__ conw, const unsigned short* __restrict__ ugb,
    const float* __restrict__ ug_bias, const unsigned short* __restrict__ cpw,
    const unsigned short* __restrict__ gcw, float* __restrict__ out) {
  __shared__ unsigned short XA[64 * 256];
  char* xab = (char*)XA;
  const int tid = threadIdx.x;
  const int lane = tid & 63;
  const int wv = tid >> 6;
  const int l15 = lane & 15;
  const int l4 = lane >> 4;
  const int n0 = blockIdx.x * 64;

#pragma unroll
  for (int i = 0; i < 4; ++i) {
    int chunk = i * 512 + tid;
    int row = chunk >> 5;
    int e0 = (chunk & 31) * 8;
    u16x8 v = *(const u16x8*)(conw + ((n0 + row) * 256 + e0));
    *(u16x8*)(xab + ((row * 512 + e0 * 2) ^ ((row & 7) << 4))) = v;
  }
  __syncthreads();

  float bg[2];
#pragma unroll
  for (int nt = 0; nt < 2; ++nt) bg[nt] = ug_bias[wv * 32 + nt * 16 + l15];
  f32x4 acc[4][2];
  GEMM64B(ugb, acc, bg);

#pragma unroll
  for (int mt = 0; mt < 4; ++mt)
#pragma unroll
    for (int nt = 0; nt < 2; ++nt) {
      int h = wv * 32 + nt * 16 + l15;
#pragma unroll
      for (int r = 0; r < 4; ++r) {
        int node = n0 + mt * 16 + 4 * l4 + r;
        float gate = fsig(bf2f(gcw[node * 256 + h]) + acc[mt][nt][r]);
        float c = bf2f(cpw[node * 256 + h]);
        float cn = bf2f(conw[node * 256 + h]);
        out[node * 256 + h] = gate * c + (1.0f - gate) * cn;
      }
    }
}

extern "C" void kernel_launch(void* const* d_in, const int* in_sizes, int n_in,
                              void* d_out, int out_size, void* d_ws, size_t ws_size,
                              hipStream_t stream) {
  (void)in_sizes; (void)n_in; (void)out_size; (void)ws_size;
  const float* x = (const float*)d_in[0];
  const int* counts = (const int*)d_in[1];
  const float* Wx_w = (const float*)d_in[2];
  const float* Wx_b = (const float*)d_in[3];
  const float* Wh_w = (const float*)d_in[4];
  const float* Wh_b = (const float*)d_in[5];
  const float* Uh_w = (const float*)d_in[6];
  const float* Uh_b = (const float*)d_in[7];
  const float* Wg_w = (const float*)d_in[8];
  const float* Wg_b = (const float*)d_in[9];
  const float* Ug_w = (const float*)d_in[10];
  const float* Ug_b = (const float*)d_in[11];

  unsigned short* ws = (unsigned short*)d_ws;
  unsigned short* wxb = ws;                    // 65536 els each
  unsigned short* whb = ws + 65536;
  unsigned short* uhb = ws + 131072;
  unsigned short* wgb = ws + 196608;
  unsigned short* ugb = ws + 262144;
  unsigned short* cpw = ws + 327680;           // 32768*256 els each
  unsigned short* hcw = cpw + NODES * 256;
  unsigned short* gcw = hcw + NODES * 256;
  unsigned short* conw = gcw + NODES * 256;
  int* perm = (int*)(conw + NODES * 256);      // 3*NODES ints (fixed regions)
  int* gcnt = perm + 3 * NODES;                // 3 ints
  float* out = (float*)d_out;

  hipLaunchKernelGGL(k_cvtw, dim3(160), dim3(256), 0, stream,
                     Wx_w, Wh_w, Uh_w, Wg_w, Ug_w, ws, gcnt);
  hipLaunchKernelGGL(k_sort, dim3(NODES / 512), dim3(512), 0, stream,
                     counts, perm, gcnt);
  hipLaunchKernelGGL(k_center, dim3(NODES / 64), dim3(512), 0, stream,
                     x, wxb, whb, wgb, Wx_b, Wh_b, Wg_b, cpw, hcw, gcw);
  hipLaunchKernelGGL(k_neigh, dim3(NODES / 4 + 3), dim3(512), 0, stream,
                     x, counts, wxb, uhb, Wx_b, Uh_b, hcw, conw, perm, gcnt);
  hipLaunchKernelGGL(k_final, dim3(NODES / 64), dim3(512), 0, stream,
                     conw, ugb, Ug_b, cpw, gcw, out);
}